// Round 1
// baseline (258.808 us; speedup 1.0000x reference)
//
#include <hip/hip_runtime.h>

#define NNODES 4096
#define DIM 512
#define QKVD 1536
#define MAXE 256

typedef __bf16 bf16_t;
typedef bf16_t bf16x8 __attribute__((ext_vector_type(8)));
typedef float f32x4 __attribute__((ext_vector_type(4)));
typedef unsigned int uint;

// ---------------- cast f32 -> bf16 ----------------
__global__ __launch_bounds__(256) void cast_f32_bf16(const float* __restrict__ src,
                                                     bf16_t* __restrict__ dst, int n4) {
  int i = blockIdx.x * 256 + threadIdx.x;
  if (i < n4) {
    float4 v = ((const float4*)src)[i];
    dst[4 * i + 0] = (bf16_t)v.x;
    dst[4 * i + 1] = (bf16_t)v.y;
    dst[4 * i + 2] = (bf16_t)v.z;
    dst[4 * i + 3] = (bf16_t)v.w;
  }
}

// ---------------- CSR build ----------------
__global__ __launch_bounds__(256) void count_edges_k(const int* __restrict__ ei,
                                                     uint* __restrict__ deg, int E) {
  int e = blockIdx.x * 256 + threadIdx.x;
  if (e < E) {
    int dst = ei[E + e] & (NNODES - 1);
    atomicAdd(&deg[dst], 1u);
  }
}

__global__ __launch_bounds__(1024) void scan_k(const uint* __restrict__ cnt,
                                               uint* __restrict__ rowptr) {
  __shared__ uint s[1024];
  int t = threadIdx.x;
  uint4 v = ((const uint4*)cnt)[t];
  uint sum = v.x + v.y + v.z + v.w;
  s[t] = sum;
  __syncthreads();
  for (int off = 1; off < 1024; off <<= 1) {
    uint x = (t >= off) ? s[t - off] : 0u;
    __syncthreads();
    s[t] += x;
    __syncthreads();
  }
  uint excl = s[t] - sum;
  rowptr[4 * t + 0] = excl;
  rowptr[4 * t + 1] = excl + v.x;
  rowptr[4 * t + 2] = excl + v.x + v.y;
  rowptr[4 * t + 3] = excl + v.x + v.y + v.z;
  if (t == 1023) rowptr[4096] = s[1023];
}

__global__ __launch_bounds__(256) void fill_csr_k(const int* __restrict__ ei,
                                                  const uint* __restrict__ rowptr,
                                                  uint* __restrict__ cursor,
                                                  int* __restrict__ colv,
                                                  uint* __restrict__ eidv, int E) {
  int e = blockIdx.x * 256 + threadIdx.x;
  if (e < E) {
    int src = ei[e] & (NNODES - 1);
    int dst = ei[E + e] & (NNODES - 1);
    uint pos = atomicAdd(&cursor[dst], 1u);
    uint o = rowptr[dst] + pos;
    colv[o] = src;
    eidv[o] = (uint)e + 1u;  // 0 reserved for the diagonal self-entry
  }
}

// ---------------- bf16 MFMA GEMM: C = A @ B^T + bias ----------------
// A: (M,K) bf16 row-major, B: (Nt,K) bf16 row-major, C: (M,Nt)
template <bool OUT_BF16>
__global__ __launch_bounds__(256) void gemm_bt(const bf16_t* __restrict__ A,
                                               const bf16_t* __restrict__ B,
                                               const float* __restrict__ bias,
                                               void* __restrict__ Cout,
                                               int M, int Nt, int K) {
  __shared__ bf16_t As[128][40];  // +8 pad: ~2-way max bank aliasing (free)
  __shared__ bf16_t Bs[128][40];
  const int t = threadIdx.x;
  const int lane = t & 63, w = t >> 6;
  const int wr = (w >> 1) * 64, wc = (w & 1) * 64;
  const int m0 = blockIdx.y * 128, n0 = blockIdx.x * 128;
  f32x4 acc[4][4] = {};
  const int r_ld = t >> 2;         // 0..63
  const int c_ld = (t & 3) * 8;    // 0,8,16,24

  for (int k0 = 0; k0 < K; k0 += 32) {
#pragma unroll
    for (int seg = 0; seg < 2; ++seg) {
      int row = r_ld + seg * 64;
      *(int4*)&As[row][c_ld] = *(const int4*)(A + (long)(m0 + row) * K + k0 + c_ld);
      *(int4*)&Bs[row][c_ld] = *(const int4*)(B + (long)(n0 + row) * K + k0 + c_ld);
    }
    __syncthreads();
    bf16x8 af[4], bfr[4];
    const int kg = (lane >> 4) * 8;
#pragma unroll
    for (int i = 0; i < 4; ++i) {
      af[i] = *(const bf16x8*)&As[wr + i * 16 + (lane & 15)][kg];
      bfr[i] = *(const bf16x8*)&Bs[wc + i * 16 + (lane & 15)][kg];
    }
#pragma unroll
    for (int i = 0; i < 4; ++i)
#pragma unroll
      for (int j = 0; j < 4; ++j)
        acc[i][j] = __builtin_amdgcn_mfma_f32_16x16x32_bf16(af[i], bfr[j], acc[i][j], 0, 0, 0);
    __syncthreads();
  }

  const int cr = (lane >> 4) * 4;  // C/D: col=lane&15, row=(lane>>4)*4+reg
  const int cc = lane & 15;
#pragma unroll
  for (int i = 0; i < 4; ++i) {
#pragma unroll
    for (int j = 0; j < 4; ++j) {
      int n = n0 + wc + j * 16 + cc;
      float bv = bias[n];
#pragma unroll
      for (int r = 0; r < 4; ++r) {
        int m = m0 + wr + i * 16 + cr + r;
        float vv = acc[i][j][r] + bv;
        if (OUT_BF16)
          ((bf16_t*)Cout)[(long)m * Nt + n] = (bf16_t)vv;
        else
          ((float*)Cout)[(long)m * Nt + n] = vv;
      }
    }
  }
}

// ---------------- sparse attention ----------------
// qkv: (N, 1536) bf16 [q|k|v]; out: (N,512) bf16, head-major columns
__global__ __launch_bounds__(256) void attn_k(const bf16_t* __restrict__ qkv,
                                              const float* __restrict__ ew,
                                              const uint* __restrict__ rowptr,
                                              const int* __restrict__ colv,
                                              const uint* __restrict__ eidv,
                                              bf16_t* __restrict__ outb) {
  __shared__ float qs[DIM];
  __shared__ float sc[8][MAXE];
  __shared__ int srcs[MAXE];
  __shared__ uint eids[MAXE];
  __shared__ int vld[MAXE];

  const int i = blockIdx.x;
  const int t = threadIdx.x;
  const int lane = t & 63, w = t >> 6;

  uint base = rowptr[i];
  uint Lr = rowptr[i + 1] - base;
  int L = (Lr < (uint)(MAXE - 1)) ? (int)Lr : (MAXE - 1);
  int n_ent = L + 1;

  for (int d = t; d < DIM; d += 256) qs[d] = (float)qkv[(long)i * QKVD + d];
  for (int e = t; e < L; e += 256) {
    srcs[e] = colv[base + e];
    eids[e] = eidv[base + e];
  }
  if (t == 0) { srcs[L] = i; eids[L] = 0u; }
  __syncthreads();

  // deterministic dedupe: an entry survives iff no entry with same src has larger eid
  for (int e = t; e < n_ent; e += 256) {
    int sj = srcs[e];
    uint my = eids[e];
    int ok = 1;
    for (int j = 0; j < n_ent; ++j)
      if (srcs[j] == sj && eids[j] > my) { ok = 0; break; }
    vld[e] = ok;
  }
  __syncthreads();

  // scores: wave w handles heads 2w, 2w+1; lane handles entries lane, lane+64, ...
#pragma unroll
  for (int hh = 0; hh < 2; ++hh) {
    int h = w * 2 + hh;
    for (int e = lane; e < n_ent; e += 64) {
      float sv;
      if (!vld[e]) {
        sv = -1e30f;
      } else {
        int cj = srcs[e];
        const bf16_t* kr = qkv + (long)cj * QKVD + DIM + h * 64;
        const float* qh = qs + h * 64;
        float s = 0.f;
#pragma unroll
        for (int d = 0; d < 64; ++d) s += qh[d] * (float)kr[d];
        float b = (eids[e] == 0u) ? 0.f : ew[eids[e] - 1u];
        sv = s * 0.125f + b;
      }
      sc[h][e] = sv;
    }
  }
  __syncthreads();

  float invs[2];
#pragma unroll
  for (int hh = 0; hh < 2; ++hh) {
    int h = w * 2 + hh;
    float m = -1e30f;
    for (int e = lane; e < n_ent; e += 64) m = fmaxf(m, sc[h][e]);
    for (int o = 32; o > 0; o >>= 1) m = fmaxf(m, __shfl_xor(m, o));
    float ps = 0.f;
    for (int e = lane; e < n_ent; e += 64) {
      float ev = __expf(sc[h][e] - m);
      sc[h][e] = ev;
      ps += ev;
    }
    for (int o = 32; o > 0; o >>= 1) ps += __shfl_xor(ps, o);
    invs[hh] = 1.f / ps;
  }
  __syncthreads();

  // PV: lane = head dim (coalesced V reads)
#pragma unroll
  for (int hh = 0; hh < 2; ++hh) {
    int h = w * 2 + hh;
    float acc = 0.f;
    for (int e = 0; e < n_ent; ++e) {
      float p = sc[h][e];
      if (p != 0.f) acc += p * (float)qkv[(long)srcs[e] * QKVD + 2 * DIM + h * 64 + lane];
    }
    outb[(long)i * DIM + h * 64 + lane] = (bf16_t)(acc * invs[hh]);
  }
}

// ---------------- LayerNorm(a+b) ----------------
__global__ __launch_bounds__(64) void ln_k(const float* __restrict__ a,
                                           const float* __restrict__ b,
                                           const float* __restrict__ g,
                                           const float* __restrict__ beta,
                                           float* __restrict__ of,
                                           bf16_t* __restrict__ ob) {
  const int row = blockIdx.x;
  const int l = threadIdx.x;
  const float* pa = a + (long)row * DIM;
  const float* pb = b + (long)row * DIM;
  float v[8];
  float s = 0.f;
#pragma unroll
  for (int j = 0; j < 8; ++j) {
    int d = l + j * 64;
    v[j] = pa[d] + pb[d];
    s += v[j];
  }
  for (int o = 32; o > 0; o >>= 1) s += __shfl_xor(s, o);
  float mu = s * (1.f / 512.f);
  float q = 0.f;
#pragma unroll
  for (int j = 0; j < 8; ++j) {
    float dd = v[j] - mu;
    q += dd * dd;
  }
  for (int o = 32; o > 0; o >>= 1) q += __shfl_xor(q, o);
  float inv = rsqrtf(q * (1.f / 512.f) + 1e-5f);
#pragma unroll
  for (int j = 0; j < 8; ++j) {
    int d = l + j * 64;
    float y = (v[j] - mu) * inv * g[d] + beta[d];
    of[(long)row * DIM + d] = y;
    if (ob) ob[(long)row * DIM + d] = (bf16_t)y;
  }
}

// ---------------- launch ----------------
extern "C" void kernel_launch(void* const* d_in, const int* in_sizes, int n_in,
                              void* d_out, int out_size, void* d_ws, size_t ws_size,
                              hipStream_t stream) {
  const float* x = (const float*)d_in[0];
  const int* ei = (const int*)d_in[1];
  const float* ew = (const float*)d_in[2];
  const float* Wqkv = (const float*)d_in[3];
  const float* bqkv = (const float*)d_in[4];
  const float* Wo = (const float*)d_in[5];
  const float* bo = (const float*)d_in[6];
  const float* W1 = (const float*)d_in[7];
  const float* b1 = (const float*)d_in[8];
  const float* g1 = (const float*)d_in[9];
  const float* be1 = (const float*)d_in[10];
  const float* g2 = (const float*)d_in[11];
  const float* be2 = (const float*)d_in[12];
  float* out = (float*)d_out;
  const int E = in_sizes[1] / 2;

  char* ws = (char*)d_ws;
  bf16_t* qkvb = (bf16_t*)(ws + 0);               // 12,582,912 B
  bf16_t* xb = (bf16_t*)(ws + 12582912);          // 4,194,304
  bf16_t* Wqkvb = (bf16_t*)(ws + 16777216);       // 1,572,864
  bf16_t* Wob = (bf16_t*)(ws + 18350080);         // 524,288
  bf16_t* W1b = (bf16_t*)(ws + 18874368);         // 524,288
  bf16_t* outb = (bf16_t*)(ws + 19398656);        // 4,194,304
  float* h = (float*)(ws + 23592960);             // 8,388,608
  bf16_t* hb = (bf16_t*)(ws + 31981568);          // 4,194,304
  float* f = (float*)(ws + 36175872);             // 8,388,608
  uint* deg = (uint*)(ws + 44564480);             // 16,384
  uint* cursor = (uint*)(ws + 44580864);          // 16,384
  uint* rowptr = (uint*)(ws + 44597248);          // 16,640 (padded)
  int* colv = (int*)(ws + 44613888);              // 524,288
  uint* eidv = (uint*)(ws + 45138176);            // 524,288
  float* attn_out = (float*)(ws + 0);             // alias over dead qkvb

  // zero deg + cursor (adjacent)
  hipMemsetAsync(deg, 0, 32768, stream);

  // casts
  cast_f32_bf16<<<(NNODES * DIM / 4 + 255) / 256, 256, 0, stream>>>(x, xb, NNODES * DIM / 4);
  cast_f32_bf16<<<(QKVD * DIM / 4 + 255) / 256, 256, 0, stream>>>(Wqkv, Wqkvb, QKVD * DIM / 4);
  cast_f32_bf16<<<(DIM * DIM / 4 + 255) / 256, 256, 0, stream>>>(Wo, Wob, DIM * DIM / 4);
  cast_f32_bf16<<<(DIM * DIM / 4 + 255) / 256, 256, 0, stream>>>(W1, W1b, DIM * DIM / 4);

  // CSR
  count_edges_k<<<(E + 255) / 256, 256, 0, stream>>>(ei, deg, E);
  scan_k<<<1, 1024, 0, stream>>>(deg, rowptr);
  fill_csr_k<<<(E + 255) / 256, 256, 0, stream>>>(ei, rowptr, cursor, colv, eidv, E);

  // QKV projection (bf16 out)
  gemm_bt<true><<<dim3(QKVD / 128, NNODES / 128), 256, 0, stream>>>(
      xb, Wqkvb, bqkv, (void*)qkvb, NNODES, QKVD, DIM);

  // sparse attention
  attn_k<<<NNODES, 256, 0, stream>>>(qkvb, ew, rowptr, colv, eidv, outb);

  // output projection (f32 out, aliases qkvb space)
  gemm_bt<false><<<dim3(DIM / 128, NNODES / 128), 256, 0, stream>>>(
      outb, Wob, bo, (void*)attn_out, NNODES, DIM, DIM);

  // LN1: h = LN(x + attn_out), also bf16 copy for FFN GEMM
  ln_k<<<NNODES, 64, 0, stream>>>(x, attn_out, g1, be1, h, hb);

  // FFN: f = hb @ W1^T + b1
  gemm_bt<false><<<dim3(DIM / 128, NNODES / 128), 256, 0, stream>>>(
      hb, W1b, b1, (void*)f, NNODES, DIM, DIM);

  // LN2 -> out
  ln_k<<<NNODES, 64, 0, stream>>>(h, f, g2, be2, out, nullptr);
}

// Round 2
// 157.940 us; speedup vs baseline: 1.6386x; 1.6386x over previous
//
#include <hip/hip_runtime.h>

#define NNODES 4096
#define DIM 512
#define QKVD 1536
#define MAXE 96  // bucket capacity per dst row (Poisson(32): P(deg>96) ~ 1e-18)

typedef __bf16 bf16_t;
typedef bf16_t bf16x8 __attribute__((ext_vector_type(8)));
typedef bf16_t bf16x2 __attribute__((ext_vector_type(2)));
typedef float f32x4 __attribute__((ext_vector_type(4)));
typedef unsigned int uint;

// ---------------- fused casts f32 -> bf16 ----------------
// ranges in float4 units: x 524288 | Wqkv 196608 | Wo 65536 | W1 65536 = 851968 total
__global__ __launch_bounds__(256) void cast_all_k(const float* __restrict__ x,
                                                  const float* __restrict__ wqkv,
                                                  const float* __restrict__ wo,
                                                  const float* __restrict__ w1,
                                                  bf16_t* __restrict__ xb,
                                                  bf16_t* __restrict__ wqkvb,
                                                  bf16_t* __restrict__ wob,
                                                  bf16_t* __restrict__ w1b) {
  int i = blockIdx.x * 256 + threadIdx.x;
  const float* src;
  bf16_t* dst;
  int off;
  if (i < 524288) { src = x; dst = xb; off = i; }
  else if (i < 720896) { src = wqkv; dst = wqkvb; off = i - 524288; }
  else if (i < 786432) { src = wo; dst = wob; off = i - 720896; }
  else { src = w1; dst = w1b; off = i - 786432; }
  float4 v = ((const float4*)src)[off];
  dst[4 * off + 0] = (bf16_t)v.x;
  dst[4 * off + 1] = (bf16_t)v.y;
  dst[4 * off + 2] = (bf16_t)v.z;
  dst[4 * off + 3] = (bf16_t)v.w;
}

// ---------------- bucket CSR fill ----------------
__global__ __launch_bounds__(256) void fill_bucket_k(const int* __restrict__ ei,
                                                     uint* __restrict__ deg,
                                                     int* __restrict__ colv,
                                                     uint* __restrict__ eidv, int E) {
  int e = blockIdx.x * 256 + threadIdx.x;
  if (e < E) {
    int src = ei[e] & (NNODES - 1);
    int dst = ei[E + e] & (NNODES - 1);
    uint pos = atomicAdd(&deg[dst], 1u);
    if (pos < MAXE) {
      colv[dst * MAXE + pos] = src;
      eidv[dst * MAXE + pos] = (uint)e + 1u;  // 0 reserved for diagonal self-entry
    }
  }
}

// ---------------- bf16 MFMA GEMM: C = A @ B^T + bias ----------------
template <bool OUT_BF16>
__global__ __launch_bounds__(256) void gemm_bt(const bf16_t* __restrict__ A,
                                               const bf16_t* __restrict__ B,
                                               const float* __restrict__ bias,
                                               void* __restrict__ Cout,
                                               int M, int Nt, int K) {
  __shared__ bf16_t As[128][40];
  __shared__ bf16_t Bs[128][40];
  const int t = threadIdx.x;
  const int lane = t & 63, w = t >> 6;
  const int wr = (w >> 1) * 64, wc = (w & 1) * 64;
  const int m0 = blockIdx.y * 128, n0 = blockIdx.x * 128;
  f32x4 acc[4][4] = {};
  const int r_ld = t >> 2;
  const int c_ld = (t & 3) * 8;

  for (int k0 = 0; k0 < K; k0 += 32) {
#pragma unroll
    for (int seg = 0; seg < 2; ++seg) {
      int row = r_ld + seg * 64;
      *(int4*)&As[row][c_ld] = *(const int4*)(A + (long)(m0 + row) * K + k0 + c_ld);
      *(int4*)&Bs[row][c_ld] = *(const int4*)(B + (long)(n0 + row) * K + k0 + c_ld);
    }
    __syncthreads();
    bf16x8 af[4], bfr[4];
    const int kg = (lane >> 4) * 8;
#pragma unroll
    for (int i = 0; i < 4; ++i) {
      af[i] = *(const bf16x8*)&As[wr + i * 16 + (lane & 15)][kg];
      bfr[i] = *(const bf16x8*)&Bs[wc + i * 16 + (lane & 15)][kg];
    }
#pragma unroll
    for (int i = 0; i < 4; ++i)
#pragma unroll
      for (int j = 0; j < 4; ++j)
        acc[i][j] = __builtin_amdgcn_mfma_f32_16x16x32_bf16(af[i], bfr[j], acc[i][j], 0, 0, 0);
    __syncthreads();
  }

  const int cr = (lane >> 4) * 4;
  const int cc = lane & 15;
#pragma unroll
  for (int i = 0; i < 4; ++i) {
#pragma unroll
    for (int j = 0; j < 4; ++j) {
      int n = n0 + wc + j * 16 + cc;
      float bv = bias[n];
#pragma unroll
      for (int r = 0; r < 4; ++r) {
        int m = m0 + wr + i * 16 + cr + r;
        float vv = acc[i][j][r] + bv;
        if (OUT_BF16)
          ((bf16_t*)Cout)[(long)m * Nt + n] = (bf16_t)vv;
        else
          ((float*)Cout)[(long)m * Nt + n] = vv;
      }
    }
  }
}

// ---------------- fused sparse attention: scores + softmax + PV ----------------
// one block (256 thr) per dst row
__global__ __launch_bounds__(256) void attn_fused_k(const bf16_t* __restrict__ qkv,
                                                    const float* __restrict__ ew,
                                                    const uint* __restrict__ deg,
                                                    const int* __restrict__ colv,
                                                    const uint* __restrict__ eidv,
                                                    bf16_t* __restrict__ outb) {
  __shared__ float sc[8][MAXE + 1];
  __shared__ int srcs[MAXE + 1];
  __shared__ uint eids[MAXE + 1];
  __shared__ int vld[MAXE + 1];

  const int i = blockIdx.x;
  const int t = threadIdx.x;
  const int lane = t & 63, w = t >> 6;

  uint dg = deg[i];
  int L = (dg < (uint)MAXE) ? (int)dg : MAXE;
  int n = L + 1;

  if (t < L) {
    srcs[t] = colv[i * MAXE + t];
    eids[t] = eidv[i * MAXE + t];
  }
  if (t == 0) { srcs[L] = i; eids[L] = 0u; }
  __syncthreads();

  // deterministic dedupe (last edge-id wins per src)
  if (t < n) {
    int sj = srcs[t];
    uint my = eids[t];
    int ok = 1;
    for (int j = 0; j < n; ++j)
      if (srcs[j] == sj && eids[j] > my) { ok = 0; break; }
    vld[t] = ok;
  }
  __syncthreads();

  // scores: wave per entry (strided); lane = 16B chunk of the 512-dim row
  const bf16x8 qv = *(const bf16x8*)(qkv + (long)i * QKVD + lane * 8);
  for (int e = w; e < n; e += 4) {
    int sj = srcs[e];
    const bf16x8 kv = *(const bf16x8*)(qkv + (long)sj * QKVD + DIM + lane * 8);
    float s = 0.f;
#pragma unroll
    for (int j = 0; j < 8; ++j) s += (float)qv[j] * (float)kv[j];
    s += __shfl_xor(s, 1);
    s += __shfl_xor(s, 2);
    s += __shfl_xor(s, 4);
    if ((lane & 7) == 0) {
      int h = lane >> 3;
      float b = (eids[e] == 0u) ? 0.f : ew[eids[e] - 1u];
      sc[h][e] = vld[e] ? (s * 0.125f + b) : -1e30f;
    }
  }
  __syncthreads();

  // softmax: wave w handles heads 2w, 2w+1 (n <= 97 -> at most 2 entries/lane)
  float inv0 = 0.f, inv1 = 0.f;
#pragma unroll
  for (int hh = 0; hh < 2; ++hh) {
    int h = w * 2 + hh;
    float m = -1e30f;
    for (int e = lane; e < n; e += 64) m = fmaxf(m, sc[h][e]);
#pragma unroll
    for (int o = 32; o > 0; o >>= 1) m = fmaxf(m, __shfl_xor(m, o));
    float ps = 0.f;
    for (int e = lane; e < n; e += 64) {
      float ev = __expf(sc[h][e] - m);
      sc[h][e] = ev;
      ps += ev;
    }
#pragma unroll
    for (int o = 32; o > 0; o >>= 1) ps += __shfl_xor(ps, o);
    if (hh == 0) inv0 = 1.f / ps; else inv1 = 1.f / ps;
  }
  // no barrier needed: each wave PV-reads only the sc rows it just wrote

  // PV: thread t covers dims 2t, 2t+1; head h = t>>5 (same heads as this wave's softmax)
  const int h = t >> 5;
  const float inv = (lane >= 32) ? inv1 : inv0;
  float ax = 0.f, ay = 0.f;
  for (int e = 0; e < n; ++e) {
    if (!vld[e]) continue;
    float p = sc[h][e];
    bf16x2 vv = *(const bf16x2*)(qkv + (long)srcs[e] * QKVD + 2 * DIM + 2 * t);
    ax += p * (float)vv[0];
    ay += p * (float)vv[1];
  }
  bf16x2 o2;
  o2[0] = (bf16_t)(ax * inv);
  o2[1] = (bf16_t)(ay * inv);
  *(bf16x2*)(outb + (long)i * DIM + 2 * t) = o2;
}

// ---------------- LayerNorm(a+b) ----------------
__global__ __launch_bounds__(64) void ln_k(const float* __restrict__ a,
                                           const float* __restrict__ b,
                                           const float* __restrict__ g,
                                           const float* __restrict__ beta,
                                           float* __restrict__ of,
                                           bf16_t* __restrict__ ob) {
  const int row = blockIdx.x;
  const int l = threadIdx.x;
  const float* pa = a + (long)row * DIM;
  const float* pb = b + (long)row * DIM;
  float v[8];
  float s = 0.f;
#pragma unroll
  for (int j = 0; j < 8; ++j) {
    int d = l + j * 64;
    v[j] = pa[d] + pb[d];
    s += v[j];
  }
#pragma unroll
  for (int o = 32; o > 0; o >>= 1) s += __shfl_xor(s, o);
  float mu = s * (1.f / 512.f);
  float q = 0.f;
#pragma unroll
  for (int j = 0; j < 8; ++j) {
    float dd = v[j] - mu;
    q += dd * dd;
  }
#pragma unroll
  for (int o = 32; o > 0; o >>= 1) q += __shfl_xor(q, o);
  float inv = rsqrtf(q * (1.f / 512.f) + 1e-5f);
#pragma unroll
  for (int j = 0; j < 8; ++j) {
    int d = l + j * 64;
    float y = (v[j] - mu) * inv * g[d] + beta[d];
    of[(long)row * DIM + d] = y;
    if (ob) ob[(long)row * DIM + d] = (bf16_t)y;
  }
}

// ---------------- launch ----------------
extern "C" void kernel_launch(void* const* d_in, const int* in_sizes, int n_in,
                              void* d_out, int out_size, void* d_ws, size_t ws_size,
                              hipStream_t stream) {
  const float* x = (const float*)d_in[0];
  const int* ei = (const int*)d_in[1];
  const float* ew = (const float*)d_in[2];
  const float* Wqkv = (const float*)d_in[3];
  const float* bqkv = (const float*)d_in[4];
  const float* Wo = (const float*)d_in[5];
  const float* bo = (const float*)d_in[6];
  const float* W1 = (const float*)d_in[7];
  const float* b1 = (const float*)d_in[8];
  const float* g1 = (const float*)d_in[9];
  const float* be1 = (const float*)d_in[10];
  const float* g2 = (const float*)d_in[11];
  const float* be2 = (const float*)d_in[12];
  float* out = (float*)d_out;
  const int E = in_sizes[1] / 2;

  char* ws = (char*)d_ws;
  bf16_t* qkvb = (bf16_t*)(ws + 0);           // 12,582,912 B
  bf16_t* xb = (bf16_t*)(ws + 12582912);      // 4,194,304
  bf16_t* Wqkvb = (bf16_t*)(ws + 16777216);   // 1,572,864
  bf16_t* Wob = (bf16_t*)(ws + 18350080);     // 524,288
  bf16_t* W1b = (bf16_t*)(ws + 18874368);     // 524,288
  bf16_t* outb = (bf16_t*)(ws + 19398656);    // 4,194,304
  float* h = (float*)(ws + 23592960);         // 8,388,608
  bf16_t* hb = (bf16_t*)(ws + 31981568);      // 4,194,304
  float* f = (float*)(ws + 36175872);         // 8,388,608 (end 44,564,480)
  // CSR buffers alias the h region (h is written only after attention is done)
  uint* deg = (uint*)(ws + 23592960);         // 16,384
  int* colv = (int*)(ws + 23609344);          // 1,572,864
  uint* eidv = (uint*)(ws + 25182208);        // 1,572,864 (end 26,755,072 < h end)
  float* attn_out = (float*)(ws + 0);         // alias over dead qkvb

  hipMemsetAsync(deg, 0, 16384, stream);

  cast_all_k<<<3328, 256, 0, stream>>>(x, Wqkv, Wo, W1, xb, Wqkvb, Wob, W1b);
  fill_bucket_k<<<(E + 255) / 256, 256, 0, stream>>>(ei, deg, colv, eidv, E);

  // QKV projection (bf16 out)
  gemm_bt<true><<<dim3(QKVD / 128, NNODES / 128), 256, 0, stream>>>(
      xb, Wqkvb, bqkv, (void*)qkvb, NNODES, QKVD, DIM);

  // fused sparse attention
  attn_fused_k<<<NNODES, 256, 0, stream>>>(qkvb, ew, deg, colv, eidv, outb);

  // output projection (f32 out, aliases qkvb space)
  gemm_bt<false><<<dim3(DIM / 128, NNODES / 128), 256, 0, stream>>>(
      outb, Wob, bo, (void*)attn_out, NNODES, DIM, DIM);

  // LN1: h = LN(x + attn_out), also bf16 copy for FFN GEMM
  ln_k<<<NNODES, 64, 0, stream>>>(x, attn_out, g1, be1, h, hb);

  // FFN: f = hb @ W1^T + b1
  gemm_bt<false><<<dim3(DIM / 128, NNODES / 128), 256, 0, stream>>>(
      hb, W1b, b1, (void*)f, NNODES, DIM, DIM);

  // LN2 -> out
  ln_k<<<NNODES, 64, 0, stream>>>(h, f, g2, be2, out, nullptr);
}

// Round 3
// 137.929 us; speedup vs baseline: 1.8764x; 1.1451x over previous
//
#include <hip/hip_runtime.h>

#define NNODES 4096
#define DIM 512
#define QKVD 1536
#define MAXE 96  // bucket capacity per dst row (Poisson(32): P(deg>96) ~ 1e-18)

typedef __bf16 bf16_t;
typedef bf16_t bf16x8 __attribute__((ext_vector_type(8)));
typedef bf16_t bf16x2 __attribute__((ext_vector_type(2)));
typedef float f32x4 __attribute__((ext_vector_type(4)));
typedef unsigned int uint;

// ---------------- fused casts f32 -> bf16 ----------------
__global__ __launch_bounds__(256) void cast_all_k(const float* __restrict__ x,
                                                  const float* __restrict__ wqkv,
                                                  const float* __restrict__ wo,
                                                  const float* __restrict__ w1,
                                                  bf16_t* __restrict__ xb,
                                                  bf16_t* __restrict__ wqkvb,
                                                  bf16_t* __restrict__ wob,
                                                  bf16_t* __restrict__ w1b) {
  int i = blockIdx.x * 256 + threadIdx.x;
  const float* src;
  bf16_t* dst;
  int off;
  if (i < 524288) { src = x; dst = xb; off = i; }
  else if (i < 720896) { src = wqkv; dst = wqkvb; off = i - 524288; }
  else if (i < 786432) { src = wo; dst = wob; off = i - 720896; }
  else { src = w1; dst = w1b; off = i - 786432; }
  float4 v = ((const float4*)src)[off];
  dst[4 * off + 0] = (bf16_t)v.x;
  dst[4 * off + 1] = (bf16_t)v.y;
  dst[4 * off + 2] = (bf16_t)v.z;
  dst[4 * off + 3] = (bf16_t)v.w;
}

// ---------------- bucket CSR fill ----------------
__global__ __launch_bounds__(256) void fill_bucket_k(const int* __restrict__ ei,
                                                     uint* __restrict__ deg,
                                                     int* __restrict__ colv,
                                                     uint* __restrict__ eidv, int E) {
  int e = blockIdx.x * 256 + threadIdx.x;
  if (e < E) {
    int src = ei[e] & (NNODES - 1);
    int dst = ei[E + e] & (NNODES - 1);
    uint pos = atomicAdd(&deg[dst], 1u);
    if (pos < MAXE) {
      colv[dst * MAXE + pos] = src;
      eidv[dst * MAXE + pos] = (uint)e + 1u;  // 0 reserved for diagonal self-entry
    }
  }
}

// ---------------- bf16 MFMA GEMM: C = A @ B^T + bias ----------------
template <bool OUT_BF16>
__global__ __launch_bounds__(256) void gemm_bt(const bf16_t* __restrict__ A,
                                               const bf16_t* __restrict__ B,
                                               const float* __restrict__ bias,
                                               void* __restrict__ Cout,
                                               int M, int Nt, int K) {
  __shared__ bf16_t As[128][40];
  __shared__ bf16_t Bs[128][40];
  const int t = threadIdx.x;
  const int lane = t & 63, w = t >> 6;
  const int wr = (w >> 1) * 64, wc = (w & 1) * 64;
  const int m0 = blockIdx.y * 128, n0 = blockIdx.x * 128;
  f32x4 acc[4][4] = {};
  const int r_ld = t >> 2;
  const int c_ld = (t & 3) * 8;

  for (int k0 = 0; k0 < K; k0 += 32) {
#pragma unroll
    for (int seg = 0; seg < 2; ++seg) {
      int row = r_ld + seg * 64;
      *(int4*)&As[row][c_ld] = *(const int4*)(A + (long)(m0 + row) * K + k0 + c_ld);
      *(int4*)&Bs[row][c_ld] = *(const int4*)(B + (long)(n0 + row) * K + k0 + c_ld);
    }
    __syncthreads();
    bf16x8 af[4], bfr[4];
    const int kg = (lane >> 4) * 8;
#pragma unroll
    for (int i = 0; i < 4; ++i) {
      af[i] = *(const bf16x8*)&As[wr + i * 16 + (lane & 15)][kg];
      bfr[i] = *(const bf16x8*)&Bs[wc + i * 16 + (lane & 15)][kg];
    }
#pragma unroll
    for (int i = 0; i < 4; ++i)
#pragma unroll
      for (int j = 0; j < 4; ++j)
        acc[i][j] = __builtin_amdgcn_mfma_f32_16x16x32_bf16(af[i], bfr[j], acc[i][j], 0, 0, 0);
    __syncthreads();
  }

  const int cr = (lane >> 4) * 4;
  const int cc = lane & 15;
#pragma unroll
  for (int i = 0; i < 4; ++i) {
#pragma unroll
    for (int j = 0; j < 4; ++j) {
      int n = n0 + wc + j * 16 + cc;
      float bv = bias[n];
#pragma unroll
      for (int r = 0; r < 4; ++r) {
        int m = m0 + wr + i * 16 + cr + r;
        float vv = acc[i][j][r] + bv;
        if (OUT_BF16)
          ((bf16_t*)Cout)[(long)m * Nt + n] = (bf16_t)vv;
        else
          ((float*)Cout)[(long)m * Nt + n] = vv;
      }
    }
  }
}

// ---------------- fused sparse attention: scores + softmax + PV ----------------
// one block (256 thr) per dst row; both score and PV are wave-parallel over entries
__global__ __launch_bounds__(256) void attn_fused_k(const bf16_t* __restrict__ qkv,
                                                    const float* __restrict__ ew,
                                                    const uint* __restrict__ deg,
                                                    const int* __restrict__ colv,
                                                    const uint* __restrict__ eidv,
                                                    bf16_t* __restrict__ outb) {
  __shared__ float sc[8][MAXE + 1];
  __shared__ int srcs[MAXE + 1];
  __shared__ uint eids[MAXE + 1];
  __shared__ int vld[MAXE + 1];
  __shared__ float invs_s[8];
  __shared__ float vacc[4][DIM];  // per-wave PV partials

  const int i = blockIdx.x;
  const int t = threadIdx.x;
  const int lane = t & 63, w = t >> 6;

  uint dg = deg[i];
  int L = (dg < (uint)MAXE) ? (int)dg : MAXE;
  int n = L + 1;

  if (t < L) {
    srcs[t] = colv[i * MAXE + t];
    eids[t] = eidv[i * MAXE + t];
  }
  if (t == L) { srcs[L] = i; eids[L] = 0u; }
  __syncthreads();

  // deterministic dedupe (last edge-id wins per src)
  if (t < n) {
    int sj = srcs[t];
    uint my = eids[t];
    int ok = 1;
    for (int j = 0; j < n; ++j)
      if (srcs[j] == sj && eids[j] > my) { ok = 0; break; }
    vld[t] = ok;
  }
  __syncthreads();

  // scores: wave per entry (strided); lane = 16B chunk of the 512-dim K row
  const bf16x8 qv = *(const bf16x8*)(qkv + (long)i * QKVD + lane * 8);
  for (int e = w; e < n; e += 4) {
    int sj = srcs[e];
    const bf16x8 kv = *(const bf16x8*)(qkv + (long)sj * QKVD + DIM + lane * 8);
    float s = 0.f;
#pragma unroll
    for (int j = 0; j < 8; ++j) s += (float)qv[j] * (float)kv[j];
    s += __shfl_xor(s, 1);
    s += __shfl_xor(s, 2);
    s += __shfl_xor(s, 4);
    if ((lane & 7) == 0) {
      int h = lane >> 3;
      float b = (eids[e] == 0u) ? 0.f : ew[eids[e] - 1u];
      sc[h][e] = vld[e] ? (s * 0.125f + b) : -1e30f;
    }
  }
  __syncthreads();

  // softmax: wave w handles heads 2w, 2w+1 (n <= 97 -> at most 2 entries/lane)
#pragma unroll
  for (int hh = 0; hh < 2; ++hh) {
    int h = w * 2 + hh;
    float m = -1e30f;
    for (int e = lane; e < n; e += 64) m = fmaxf(m, sc[h][e]);
#pragma unroll
    for (int o = 32; o > 0; o >>= 1) m = fmaxf(m, __shfl_xor(m, o));
    float ps = 0.f;
    for (int e = lane; e < n; e += 64) {
      float ev = __expf(sc[h][e] - m);
      sc[h][e] = ev;  // invalid entries become exactly 0
      ps += ev;
    }
#pragma unroll
    for (int o = 32; o > 0; o >>= 1) ps += __shfl_xor(ps, o);
    if (lane == 0) invs_s[h] = 1.f / ps;
  }
  __syncthreads();

  // PV: wave-parallel over entries; lane covers dims lane*8..lane*8+7 (coalesced 1KB/row)
  // branch-free: p==0 for invalid entries already
  const int hl = lane >> 3;
  float a8[8] = {0.f, 0.f, 0.f, 0.f, 0.f, 0.f, 0.f, 0.f};
  for (int e = w; e < n; e += 4) {
    const bf16x8 vv = *(const bf16x8*)(qkv + (long)srcs[e] * QKVD + 2 * DIM + lane * 8);
    float p = sc[hl][e];
#pragma unroll
    for (int j = 0; j < 8; ++j) a8[j] += p * (float)vv[j];
  }
#pragma unroll
  for (int j = 0; j < 8; ++j) vacc[w][lane * 8 + j] = a8[j];
  __syncthreads();

  // final cross-wave reduce: thread t -> dims 2t, 2t+1
  {
    const int d0 = 2 * t;
    const int h = t >> 5;
    const float inv = invs_s[h];
    float s0 = vacc[0][d0] + vacc[1][d0] + vacc[2][d0] + vacc[3][d0];
    float s1 = vacc[0][d0 + 1] + vacc[1][d0 + 1] + vacc[2][d0 + 1] + vacc[3][d0 + 1];
    bf16x2 o2;
    o2[0] = (bf16_t)(s0 * inv);
    o2[1] = (bf16_t)(s1 * inv);
    *(bf16x2*)(outb + (long)i * DIM + d0) = o2;
  }
}

// ---------------- LayerNorm(a+b) ----------------
__global__ __launch_bounds__(64) void ln_k(const float* __restrict__ a,
                                           const float* __restrict__ b,
                                           const float* __restrict__ g,
                                           const float* __restrict__ beta,
                                           float* __restrict__ of,
                                           bf16_t* __restrict__ ob) {
  const int row = blockIdx.x;
  const int l = threadIdx.x;
  const float* pa = a + (long)row * DIM;
  const float* pb = b + (long)row * DIM;
  float v[8];
  float s = 0.f;
#pragma unroll
  for (int j = 0; j < 8; ++j) {
    int d = l + j * 64;
    v[j] = pa[d] + pb[d];
    s += v[j];
  }
#pragma unroll
  for (int o = 32; o > 0; o >>= 1) s += __shfl_xor(s, o);
  float mu = s * (1.f / 512.f);
  float q = 0.f;
#pragma unroll
  for (int j = 0; j < 8; ++j) {
    float dd = v[j] - mu;
    q += dd * dd;
  }
#pragma unroll
  for (int o = 32; o > 0; o >>= 1) q += __shfl_xor(q, o);
  float inv = rsqrtf(q * (1.f / 512.f) + 1e-5f);
#pragma unroll
  for (int j = 0; j < 8; ++j) {
    int d = l + j * 64;
    float y = (v[j] - mu) * inv * g[d] + beta[d];
    of[(long)row * DIM + d] = y;
    if (ob) ob[(long)row * DIM + d] = (bf16_t)y;
  }
}

// ---------------- launch ----------------
extern "C" void kernel_launch(void* const* d_in, const int* in_sizes, int n_in,
                              void* d_out, int out_size, void* d_ws, size_t ws_size,
                              hipStream_t stream) {
  const float* x = (const float*)d_in[0];
  const int* ei = (const int*)d_in[1];
  const float* ew = (const float*)d_in[2];
  const float* Wqkv = (const float*)d_in[3];
  const float* bqkv = (const float*)d_in[4];
  const float* Wo = (const float*)d_in[5];
  const float* bo = (const float*)d_in[6];
  const float* W1 = (const float*)d_in[7];
  const float* b1 = (const float*)d_in[8];
  const float* g1 = (const float*)d_in[9];
  const float* be1 = (const float*)d_in[10];
  const float* g2 = (const float*)d_in[11];
  const float* be2 = (const float*)d_in[12];
  float* out = (float*)d_out;
  const int E = in_sizes[1] / 2;

  char* ws = (char*)d_ws;
  bf16_t* qkvb = (bf16_t*)(ws + 0);           // 12,582,912 B
  bf16_t* xb = (bf16_t*)(ws + 12582912);      // 4,194,304
  bf16_t* Wqkvb = (bf16_t*)(ws + 16777216);   // 1,572,864
  bf16_t* Wob = (bf16_t*)(ws + 18350080);     // 524,288
  bf16_t* W1b = (bf16_t*)(ws + 18874368);     // 524,288
  bf16_t* outb = (bf16_t*)(ws + 19398656);    // 4,194,304
  float* h = (float*)(ws + 23592960);         // 8,388,608
  bf16_t* hb = (bf16_t*)(ws + 31981568);      // 4,194,304
  float* f = (float*)(ws + 36175872);         // 8,388,608 (end 44,564,480)
  // CSR buffers alias the h region (h is written only after attention is done)
  uint* deg = (uint*)(ws + 23592960);         // 16,384
  int* colv = (int*)(ws + 23609344);          // 1,572,864
  uint* eidv = (uint*)(ws + 25182208);        // 1,572,864 (end 26,755,072 < h end)
  float* attn_out = (float*)(ws + 0);         // alias over dead qkvb

  hipMemsetAsync(deg, 0, 16384, stream);

  cast_all_k<<<3328, 256, 0, stream>>>(x, Wqkv, Wo, W1, xb, Wqkvb, Wob, W1b);
  fill_bucket_k<<<(E + 255) / 256, 256, 0, stream>>>(ei, deg, colv, eidv, E);

  // QKV projection (bf16 out)
  gemm_bt<true><<<dim3(QKVD / 128, NNODES / 128), 256, 0, stream>>>(
      xb, Wqkvb, bqkv, (void*)qkvb, NNODES, QKVD, DIM);

  // fused sparse attention
  attn_fused_k<<<NNODES, 256, 0, stream>>>(qkvb, ew, deg, colv, eidv, outb);

  // output projection (f32 out, aliases qkvb space)
  gemm_bt<false><<<dim3(DIM / 128, NNODES / 128), 256, 0, stream>>>(
      outb, Wob, bo, (void*)attn_out, NNODES, DIM, DIM);

  // LN1: h = LN(x + attn_out), also bf16 copy for FFN GEMM
  ln_k<<<NNODES, 64, 0, stream>>>(x, attn_out, g1, be1, h, hb);

  // FFN: f = hb @ W1^T + b1
  gemm_bt<false><<<dim3(DIM / 128, NNODES / 128), 256, 0, stream>>>(
      hb, W1b, b1, (void*)f, NNODES, DIM, DIM);

  // LN2 -> out
  ln_k<<<NNODES, 64, 0, stream>>>(h, f, g2, be2, out, nullptr);
}

// Round 4
// 119.173 us; speedup vs baseline: 2.1717x; 1.1574x over previous
//
#include <hip/hip_runtime.h>

#define NNODES 4096
#define DIM 512
#define QKVD 1536
#define MAXE 96  // bucket capacity per dst row (Poisson(32): P(deg>96) ~ 1e-18)

typedef __bf16 bf16_t;
typedef bf16_t bf16x8 __attribute__((ext_vector_type(8)));
typedef bf16_t bf16x2 __attribute__((ext_vector_type(2)));
typedef float f32x4 __attribute__((ext_vector_type(4)));
typedef unsigned int uint;

// ---------------- fused casts f32 -> bf16 (+ deg zero) ----------------
__global__ __launch_bounds__(256) void cast_all_k(const float* __restrict__ x,
                                                  const float* __restrict__ wqkv,
                                                  const float* __restrict__ wo,
                                                  const float* __restrict__ w1,
                                                  bf16_t* __restrict__ xb,
                                                  bf16_t* __restrict__ wqkvb,
                                                  bf16_t* __restrict__ wob,
                                                  bf16_t* __restrict__ w1b,
                                                  uint* __restrict__ deg) {
  int i = blockIdx.x * 256 + threadIdx.x;
  if (blockIdx.x < 16) deg[i] = 0u;  // 16*256 = 4096 rows
  const float* src;
  bf16_t* dst;
  int off;
  if (i < 524288) { src = x; dst = xb; off = i; }
  else if (i < 720896) { src = wqkv; dst = wqkvb; off = i - 524288; }
  else if (i < 786432) { src = wo; dst = wob; off = i - 720896; }
  else { src = w1; dst = w1b; off = i - 786432; }
  float4 v = ((const float4*)src)[off];
  dst[4 * off + 0] = (bf16_t)v.x;
  dst[4 * off + 1] = (bf16_t)v.y;
  dst[4 * off + 2] = (bf16_t)v.z;
  dst[4 * off + 3] = (bf16_t)v.w;
}

// ---------------- bucket CSR fill ----------------
__global__ __launch_bounds__(256) void fill_bucket_k(const int* __restrict__ ei,
                                                     uint* __restrict__ deg,
                                                     int* __restrict__ colv,
                                                     uint* __restrict__ eidv, int E) {
  int e = blockIdx.x * 256 + threadIdx.x;
  if (e < E) {
    int src = ei[e] & (NNODES - 1);
    int dst = ei[E + e] & (NNODES - 1);
    uint pos = atomicAdd(&deg[dst], 1u);
    if (pos < MAXE) {
      colv[dst * MAXE + pos] = src;
      eidv[dst * MAXE + pos] = (uint)e + 1u;  // 0 reserved for diagonal self-entry
    }
  }
}

// ---------------- bf16 MFMA GEMM: C = A @ B^T + bias, tile 128x64 ----------------
template <bool OUT_BF16>
__global__ __launch_bounds__(256) void gemm_bt(const bf16_t* __restrict__ A,
                                               const bf16_t* __restrict__ B,
                                               const float* __restrict__ bias,
                                               void* __restrict__ Cout,
                                               int M, int Nt, int K) {
  __shared__ bf16_t As[128][40];
  __shared__ bf16_t Bs[64][40];
  const int t = threadIdx.x;
  const int lane = t & 63, w = t >> 6;
  const int wr = (w >> 1) * 64, wc = (w & 1) * 32;  // wave covers 64x32
  const int m0 = blockIdx.y * 128, n0 = blockIdx.x * 64;
  f32x4 acc[4][2] = {};
  const int r_ld = t >> 2;         // 0..63
  const int c_ld = (t & 3) * 8;    // 0,8,16,24

  for (int k0 = 0; k0 < K; k0 += 32) {
    *(int4*)&As[r_ld][c_ld] = *(const int4*)(A + (long)(m0 + r_ld) * K + k0 + c_ld);
    *(int4*)&As[r_ld + 64][c_ld] = *(const int4*)(A + (long)(m0 + r_ld + 64) * K + k0 + c_ld);
    *(int4*)&Bs[r_ld][c_ld] = *(const int4*)(B + (long)(n0 + r_ld) * K + k0 + c_ld);
    __syncthreads();
    bf16x8 af[4], bfr[2];
    const int kg = (lane >> 4) * 8;
#pragma unroll
    for (int i = 0; i < 4; ++i)
      af[i] = *(const bf16x8*)&As[wr + i * 16 + (lane & 15)][kg];
#pragma unroll
    for (int j = 0; j < 2; ++j)
      bfr[j] = *(const bf16x8*)&Bs[wc + j * 16 + (lane & 15)][kg];
#pragma unroll
    for (int i = 0; i < 4; ++i)
#pragma unroll
      for (int j = 0; j < 2; ++j)
        acc[i][j] = __builtin_amdgcn_mfma_f32_16x16x32_bf16(af[i], bfr[j], acc[i][j], 0, 0, 0);
    __syncthreads();
  }

  const int cr = (lane >> 4) * 4;  // C/D: col=lane&15, row=(lane>>4)*4+reg
  const int cc = lane & 15;
#pragma unroll
  for (int i = 0; i < 4; ++i) {
#pragma unroll
    for (int j = 0; j < 2; ++j) {
      int n = n0 + wc + j * 16 + cc;
      float bv = bias[n];
#pragma unroll
      for (int r = 0; r < 4; ++r) {
        int m = m0 + wr + i * 16 + cr + r;
        float vv = acc[i][j][r] + bv;
        if (OUT_BF16)
          ((bf16_t*)Cout)[(long)m * Nt + n] = (bf16_t)vv;
        else
          ((float*)Cout)[(long)m * Nt + n] = vv;
      }
    }
  }
}

// ---------------- fused sparse attention: scores + softmax + PV ----------------
// one block (256 thr) per dst row; score/PV wave-parallel over entries, 2-way unrolled
__global__ __launch_bounds__(256) void attn_fused_k(const bf16_t* __restrict__ qkv,
                                                    const float* __restrict__ ew,
                                                    const uint* __restrict__ deg,
                                                    const int* __restrict__ colv,
                                                    const uint* __restrict__ eidv,
                                                    bf16_t* __restrict__ outb) {
  __shared__ float sc[8][MAXE + 1];
  __shared__ int srcs[MAXE + 1];
  __shared__ uint eids[MAXE + 1];
  __shared__ int vld[MAXE + 1];
  __shared__ float invs_s[8];
  __shared__ float vacc[4][DIM];

  const int i = blockIdx.x;
  const int t = threadIdx.x;
  const int lane = t & 63, w = t >> 6;

  uint dg = deg[i];
  int L = (dg < (uint)MAXE) ? (int)dg : MAXE;
  int n = L + 1;

  if (t < L) {
    srcs[t] = colv[i * MAXE + t];
    eids[t] = eidv[i * MAXE + t];
  }
  if (t == L) { srcs[L] = i; eids[L] = 0u; }
  __syncthreads();

  // deterministic dedupe (last edge-id wins per src)
  if (t < n) {
    int sj = srcs[t];
    uint my = eids[t];
    int ok = 1;
    for (int j = 0; j < n; ++j)
      if (srcs[j] == sj && eids[j] > my) { ok = 0; break; }
    vld[t] = ok;
  }
  __syncthreads();

  // scores: wave per entry (stride 4), 2-way unrolled; lane = 16B chunk of K row
  const bf16x8 qv = *(const bf16x8*)(qkv + (long)i * QKVD + lane * 8);
  {
    int e = w;
    for (; e + 4 < n; e += 8) {
      int sa = srcs[e], sb = srcs[e + 4];
      const bf16x8 ka = *(const bf16x8*)(qkv + (long)sa * QKVD + DIM + lane * 8);
      const bf16x8 kb = *(const bf16x8*)(qkv + (long)sb * QKVD + DIM + lane * 8);
      float s0 = 0.f, s1 = 0.f;
#pragma unroll
      for (int j = 0; j < 8; ++j) {
        s0 += (float)qv[j] * (float)ka[j];
        s1 += (float)qv[j] * (float)kb[j];
      }
      s0 += __shfl_xor(s0, 1); s1 += __shfl_xor(s1, 1);
      s0 += __shfl_xor(s0, 2); s1 += __shfl_xor(s1, 2);
      s0 += __shfl_xor(s0, 4); s1 += __shfl_xor(s1, 4);
      if ((lane & 7) == 0) {
        int h = lane >> 3;
        float b0 = (eids[e] == 0u) ? 0.f : ew[eids[e] - 1u];
        float b1 = (eids[e + 4] == 0u) ? 0.f : ew[eids[e + 4] - 1u];
        sc[h][e] = vld[e] ? (s0 * 0.125f + b0) : -1e30f;
        sc[h][e + 4] = vld[e + 4] ? (s1 * 0.125f + b1) : -1e30f;
      }
    }
    if (e < n) {
      int sa = srcs[e];
      const bf16x8 ka = *(const bf16x8*)(qkv + (long)sa * QKVD + DIM + lane * 8);
      float s0 = 0.f;
#pragma unroll
      for (int j = 0; j < 8; ++j) s0 += (float)qv[j] * (float)ka[j];
      s0 += __shfl_xor(s0, 1);
      s0 += __shfl_xor(s0, 2);
      s0 += __shfl_xor(s0, 4);
      if ((lane & 7) == 0) {
        int h = lane >> 3;
        float b0 = (eids[e] == 0u) ? 0.f : ew[eids[e] - 1u];
        sc[h][e] = vld[e] ? (s0 * 0.125f + b0) : -1e30f;
      }
    }
  }
  __syncthreads();

  // softmax: wave w handles heads 2w, 2w+1
#pragma unroll
  for (int hh = 0; hh < 2; ++hh) {
    int h = w * 2 + hh;
    float m = -1e30f;
    for (int e = lane; e < n; e += 64) m = fmaxf(m, sc[h][e]);
#pragma unroll
    for (int o = 32; o > 0; o >>= 1) m = fmaxf(m, __shfl_xor(m, o));
    float ps = 0.f;
    for (int e = lane; e < n; e += 64) {
      float ev = __expf(sc[h][e] - m);
      sc[h][e] = ev;  // invalid entries become exactly 0
      ps += ev;
    }
#pragma unroll
    for (int o = 32; o > 0; o >>= 1) ps += __shfl_xor(ps, o);
    if (lane == 0) invs_s[h] = 1.f / ps;
  }
  __syncthreads();

  // PV: wave-parallel over entries (stride 4), 2-way unrolled; lane = 8 dims
  const int hl = lane >> 3;
  float a8[8] = {0.f, 0.f, 0.f, 0.f, 0.f, 0.f, 0.f, 0.f};
  {
    int e = w;
    for (; e + 4 < n; e += 8) {
      const bf16x8 v0 = *(const bf16x8*)(qkv + (long)srcs[e] * QKVD + 2 * DIM + lane * 8);
      const bf16x8 v1 = *(const bf16x8*)(qkv + (long)srcs[e + 4] * QKVD + 2 * DIM + lane * 8);
      float p0 = sc[hl][e], p1 = sc[hl][e + 4];
#pragma unroll
      for (int j = 0; j < 8; ++j) a8[j] += p0 * (float)v0[j] + p1 * (float)v1[j];
    }
    if (e < n) {
      const bf16x8 v0 = *(const bf16x8*)(qkv + (long)srcs[e] * QKVD + 2 * DIM + lane * 8);
      float p0 = sc[hl][e];
#pragma unroll
      for (int j = 0; j < 8; ++j) a8[j] += p0 * (float)v0[j];
    }
  }
#pragma unroll
  for (int j = 0; j < 8; ++j) vacc[w][lane * 8 + j] = a8[j];
  __syncthreads();

  // final cross-wave reduce: thread t -> dims 2t, 2t+1
  {
    const int d0 = 2 * t;
    const int h = t >> 5;
    const float inv = invs_s[h];
    float s0 = vacc[0][d0] + vacc[1][d0] + vacc[2][d0] + vacc[3][d0];
    float s1 = vacc[0][d0 + 1] + vacc[1][d0 + 1] + vacc[2][d0 + 1] + vacc[3][d0 + 1];
    bf16x2 o2;
    o2[0] = (bf16_t)(s0 * inv);
    o2[1] = (bf16_t)(s1 * inv);
    *(bf16x2*)(outb + (long)i * DIM + d0) = o2;
  }
}

// ---------------- LayerNorm(a+b) ----------------
__global__ __launch_bounds__(64) void ln_k(const float* __restrict__ a,
                                           const float* __restrict__ b,
                                           const float* __restrict__ g,
                                           const float* __restrict__ beta,
                                           float* __restrict__ of,
                                           bf16_t* __restrict__ ob) {
  const int row = blockIdx.x;
  const int l = threadIdx.x;
  const float* pa = a + (long)row * DIM;
  const float* pb = b + (long)row * DIM;
  float v[8];
  float s = 0.f;
#pragma unroll
  for (int j = 0; j < 8; ++j) {
    int d = l + j * 64;
    v[j] = pa[d] + pb[d];
    s += v[j];
  }
#pragma unroll
  for (int o = 32; o > 0; o >>= 1) s += __shfl_xor(s, o);
  float mu = s * (1.f / 512.f);
  float q = 0.f;
#pragma unroll
  for (int j = 0; j < 8; ++j) {
    float dd = v[j] - mu;
    q += dd * dd;
  }
#pragma unroll
  for (int o = 32; o > 0; o >>= 1) q += __shfl_xor(q, o);
  float inv = rsqrtf(q * (1.f / 512.f) + 1e-5f);
#pragma unroll
  for (int j = 0; j < 8; ++j) {
    int d = l + j * 64;
    float y = (v[j] - mu) * inv * g[d] + beta[d];
    of[(long)row * DIM + d] = y;
    if (ob) ob[(long)row * DIM + d] = (bf16_t)y;
  }
}

// ---------------- launch ----------------
extern "C" void kernel_launch(void* const* d_in, const int* in_sizes, int n_in,
                              void* d_out, int out_size, void* d_ws, size_t ws_size,
                              hipStream_t stream) {
  const float* x = (const float*)d_in[0];
  const int* ei = (const int*)d_in[1];
  const float* ew = (const float*)d_in[2];
  const float* Wqkv = (const float*)d_in[3];
  const float* bqkv = (const float*)d_in[4];
  const float* Wo = (const float*)d_in[5];
  const float* bo = (const float*)d_in[6];
  const float* W1 = (const float*)d_in[7];
  const float* b1 = (const float*)d_in[8];
  const float* g1 = (const float*)d_in[9];
  const float* be1 = (const float*)d_in[10];
  const float* g2 = (const float*)d_in[11];
  const float* be2 = (const float*)d_in[12];
  float* out = (float*)d_out;
  const int E = in_sizes[1] / 2;

  char* ws = (char*)d_ws;
  bf16_t* qkvb = (bf16_t*)(ws + 0);           // 12,582,912 B
  bf16_t* xb = (bf16_t*)(ws + 12582912);      // 4,194,304
  bf16_t* Wqkvb = (bf16_t*)(ws + 16777216);   // 1,572,864
  bf16_t* Wob = (bf16_t*)(ws + 18350080);     // 524,288
  bf16_t* W1b = (bf16_t*)(ws + 18874368);     // 524,288
  bf16_t* outb = (bf16_t*)(ws + 19398656);    // 4,194,304
  float* h = (float*)(ws + 23592960);         // 8,388,608
  bf16_t* hb = (bf16_t*)(ws + 31981568);      // 4,194,304
  float* f = (float*)(ws + 36175872);         // 8,388,608 (end 44,564,480)
  // CSR buffers alias the h region (h is written only after attention is done)
  uint* deg = (uint*)(ws + 23592960);         // 16,384
  int* colv = (int*)(ws + 23609344);          // 1,572,864
  uint* eidv = (uint*)(ws + 25182208);        // 1,572,864 (end 26,755,072 < h end)
  float* attn_out = (float*)(ws + 0);         // alias over dead qkvb

  cast_all_k<<<3328, 256, 0, stream>>>(x, Wqkv, Wo, W1, xb, Wqkvb, Wob, W1b, deg);
  fill_bucket_k<<<(E + 255) / 256, 256, 0, stream>>>(ei, deg, colv, eidv, E);

  // QKV projection (bf16 out): 24 x 32 = 768 blocks (3 exact fill rounds)
  gemm_bt<true><<<dim3(QKVD / 64, NNODES / 128), 256, 0, stream>>>(
      xb, Wqkvb, bqkv, (void*)qkvb, NNODES, QKVD, DIM);

  // fused sparse attention
  attn_fused_k<<<NNODES, 256, 0, stream>>>(qkvb, ew, deg, colv, eidv, outb);

  // output projection (f32 out, aliases qkvb space): 8 x 32 = 256 blocks
  gemm_bt<false><<<dim3(DIM / 64, NNODES / 128), 256, 0, stream>>>(
      outb, Wob, bo, (void*)attn_out, NNODES, DIM, DIM);

  // LN1: h = LN(x + attn_out), also bf16 copy for FFN GEMM
  ln_k<<<NNODES, 64, 0, stream>>>(x, attn_out, g1, be1, h, hb);

  // FFN: f = hb @ W1^T + b1
  gemm_bt<false><<<dim3(DIM / 64, NNODES / 128), 256, 0, stream>>>(
      hb, W1b, b1, (void*)f, NNODES, DIM, DIM);

  // LN2 -> out
  ln_k<<<NNODES, 64, 0, stream>>>(h, f, g2, be2, out, nullptr);
}